// Round 1
// baseline (22699.686 us; speedup 1.0000x reference)
//
#include <hip/hip_runtime.h>
#include <stdint.h>

typedef unsigned short u16;
typedef unsigned long long u64;
typedef __attribute__((ext_vector_type(8))) short short8;
typedef __attribute__((ext_vector_type(4))) float f32x4;

__device__ __forceinline__ u16 f2bf(float f) {
  union { float f; uint32_t u; } x; x.f = f;
  uint32_t u = x.u;
  uint32_t r = (u + 0x7fffu + ((u >> 16) & 1u)) >> 16;
  return (u16)r;
}
__device__ __forceinline__ float bf2f(u16 h) {
  union { uint32_t u; float f; } x; x.u = ((uint32_t)h) << 16;
  return x.f;
}

#define NX 16777216   // 32*512*1024
#define NWI 4194304   // 4096*1024

// ---------------- prep: fp32 -> bf16 for x, Wi; bias = bi + bh ----------------
__global__ __launch_bounds__(256) void prep_kernel(
    const float* __restrict__ x, const float* __restrict__ Wi,
    const float* __restrict__ bi, const float* __restrict__ bh,
    u16* __restrict__ xbf, u16* __restrict__ wibf, float* __restrict__ bias) {
  int tid = blockIdx.x * blockDim.x + threadIdx.x;
  int stride = gridDim.x * blockDim.x;
  const int nx4 = NX / 4, nw4 = NWI / 4;
  for (int i = tid; i < nx4 + nw4; i += stride) {
    float4 v = (i < nx4) ? ((const float4*)x)[i] : ((const float4*)Wi)[i - nx4];
    ushort4 o;
    o.x = f2bf(v.x); o.y = f2bf(v.y); o.z = f2bf(v.z); o.w = f2bf(v.w);
    if (i < nx4) ((ushort4*)xbf)[i] = o; else ((ushort4*)wibf)[i - nx4] = o;
  }
  for (int i = tid; i < 4096; i += stride) bias[i] = bi[i] + bh[i];
}

// ---------------- x_proj GEMM: D[m][n] = sum_k A[m][k]*Wi[n][k] + bias[n] -----
// m = t*32 + b  (xproj layout [T][B][4H], bf16 out)
__global__ __launch_bounds__(256) void gemm_xproj(
    const u16* __restrict__ xbf, const u16* __restrict__ wibf,
    const float* __restrict__ bias, u16* __restrict__ xproj) {
  __shared__ __align__(16) short Als[8192];  // 1024 16B chunks, [k8][m] XOR-swizzled
  __shared__ __align__(16) short Bls[8192];
  const int tid = threadIdx.x;
  const int lane = tid & 63;
  const int wv = tid >> 6;
  const int nb = blockIdx.x, mb = blockIdx.y;

  int offA[4], offB[4], ldsO[4];
#pragma unroll
  for (int i = 0; i < 4; ++i) {
    int s = i * 256 + tid;
    int m = s >> 3, k8 = s & 7;
    int mg = mb * 128 + m;                 // row of xproj = t*32+b
    offA[i] = ((mg & 31) * 512 + (mg >> 5)) * 1024 + k8 * 8;  // x[b][t][k8*8]
    int ng = nb * 128 + m;
    offB[i] = ng * 1024 + k8 * 8;
    ldsO[i] = (k8 * 128 + (m ^ k8)) * 8;
  }

  f32x4 acc[4][4];
#pragma unroll
  for (int a = 0; a < 4; ++a)
#pragma unroll
    for (int b = 0; b < 4; ++b) acc[a][b] = {0.f, 0.f, 0.f, 0.f};

  const int wm = wv >> 1, wn = wv & 1;
  const int q = lane >> 4, l15 = lane & 15;

  for (int k0 = 0; k0 < 1024; k0 += 64) {
    __syncthreads();
#pragma unroll
    for (int i = 0; i < 4; ++i) {
      short8 va = *(const short8*)(xbf + offA[i] + k0);
      short8 vb = *(const short8*)(wibf + offB[i] + k0);
      *(short8*)&Als[ldsO[i]] = va;
      *(short8*)&Bls[ldsO[i]] = vb;
    }
    __syncthreads();
#pragma unroll
    for (int kk = 0; kk < 2; ++kk) {
      int k8r = kk * 4 + q;
      short8 af[4], bfv[4];
#pragma unroll
      for (int im = 0; im < 4; ++im) {
        int ml = wm * 64 + im * 16 + l15;
        af[im] = *(const short8*)&Als[(k8r * 128 + (ml ^ k8r)) * 8];
      }
#pragma unroll
      for (int in = 0; in < 4; ++in) {
        int nl = wn * 64 + in * 16 + l15;
        bfv[in] = *(const short8*)&Bls[(k8r * 128 + (nl ^ k8r)) * 8];
      }
#pragma unroll
      for (int im = 0; im < 4; ++im)
#pragma unroll
        for (int in = 0; in < 4; ++in)
          acc[im][in] = __builtin_amdgcn_mfma_f32_16x16x32_bf16(
              af[im], bfv[in], acc[im][in], 0, 0, 0);
    }
  }
  // epilogue: C/D layout col=lane&15, row=(lane>>4)*4+reg
#pragma unroll
  for (int im = 0; im < 4; ++im) {
    int row0 = mb * 128 + wm * 64 + im * 16 + q * 4;
#pragma unroll
    for (int in = 0; in < 4; ++in) {
      int col = nb * 128 + wn * 64 + in * 16 + l15;
      float bc = bias[col];
#pragma unroll
      for (int r = 0; r < 4; ++r) {
        float v = acc[im][in][r] + bc;
        xproj[(size_t)(row0 + r) * 4096 + col] = f2bf(v);
      }
    }
  }
}

// ---------------- recurrence: 32 wgs x 32 hidden units each -------------------
// Same data-embedded epoch-tag protocol as before (tag(t)=((t>>1)+1)&1 in each
// stored h bf16 LSB, double-buffered slots, producer vmcnt(0) drain before
// publish). Structural changes vs the 128-wg version:
//   * 4x fewer sync participants and 4x less poll traffic (contention was the
//     dominant cost: MfmaUtil 1.9%, ~550MB of L2-miss poll fetch per dispatch).
//   * each wave keeps 128 gate-columns of Wh resident (bfr[8][4] = 128 VGPRs),
//     K-slice 128 unchanged -> poll/A-fragment code identical.
//   * cross-wave K-reduce via ds_add_f32 (unsafeAtomicAdd) into pg[32][132]
//     (17KB LDS), each thread re-zeros exactly the 8 entries only it reads.
//   * cell state lives in registers (static thread->(b,j) map), not LDS.
__global__ __launch_bounds__(512, 2) void lstm_rec(
    const float* __restrict__ Wh, const u16* __restrict__ xproj,
    const float* __restrict__ h0, const float* __restrict__ c0,
    float* __restrict__ out, u16* __restrict__ hbuf) {
  __shared__ float pg[32][132];  // [batch][gate*32+jj]; stride 132 -> <=2-way banks
  const int tid = threadIdx.x, lane = tid & 63, w = tid >> 6;
  const int wg = blockIdx.x;
  const int hid0 = wg * 32;
  const int ks = w * 128;
  const int bl = lane & 15, q = lane >> 4;
  const int b0 = tid >> 5, jj = tid & 31;  // epilogue pair 0 (batches 0..15)
  const int b1 = b0 + 16;                  // epilogue pair 1 (batches 16..31)

  // load Wh B-fragments into registers (once): bfr[ni][kk], col = ni*16+bl,
  // gate = col>>5, hid unit = col&31
  short8 bfr[8][4];
#pragma unroll
  for (int ni = 0; ni < 8; ++ni) {
    int c = ni * 16 + bl;
    int grow = (c >> 5) * 1024 + hid0 + (c & 31);
    const float* wp = Wh + (size_t)grow * 1024 + ks + q * 8;
#pragma unroll
    for (int kk = 0; kk < 4; ++kk) {
      short8 v;
#pragma unroll
      for (int e = 0; e < 8; ++e) v[e] = (short)f2bf(wp[kk * 32 + e]);
      bfr[ni][kk] = v;
    }
  }

  // cell state in registers; publish h0 slice with tag 1 (epoch 0)
  float cs0 = c0[b0 * 1024 + hid0 + jj];
  float cs1 = c0[b1 * 1024 + hid0 + jj];
  {
    u16 hv0 = (u16)((f2bf(h0[b0 * 1024 + hid0 + jj]) & 0xFFFEu) | 1u);
    u16 hv1 = (u16)((f2bf(h0[b1 * 1024 + hid0 + jj]) & 0xFFFEu) | 1u);
    __hip_atomic_store(&hbuf[b0 * 1024 + hid0 + jj], hv0,
                       __ATOMIC_RELAXED, __HIP_MEMORY_SCOPE_AGENT);
    __hip_atomic_store(&hbuf[b1 * 1024 + hid0 + jj], hv1,
                       __ATOMIC_RELAXED, __HIP_MEMORY_SCOPE_AGENT);
  }

  // zero the 8 pg entries this thread (and only this thread) will read
#pragma unroll
  for (int g = 0; g < 4; ++g) {
    pg[b0][g * 32 + jj] = 0.f;
    pg[b1][g * 32 + jj] = 0.f;
  }
  __syncthreads();

  // A-fragment u64 indices within a slot (identical to proven 128-wg version)
  int aidx[2][4];
#pragma unroll
  for (int mi = 0; mi < 2; ++mi)
#pragma unroll
    for (int kk = 0; kk < 4; ++kk)
      aidx[mi][kk] = ((mi * 16 + bl) * 1024 + ks + q * 8 + kk * 32) >> 2;

  const u64 M = 0x0001000100010001ULL;

  for (int t = 0; t < 512; ++t) {
    const u64 E = (((t >> 1) + 1) & 1) ? M : 0ULL;
    const u64* cur = (const u64*)(hbuf + (t & 1) * 32768);
    u16* nxt = hbuf + ((t + 1) & 1) * 32768;

    // prefetch xproj gates early (independent of h)
    float xg0, xg1, xg2, xg3, xg4, xg5, xg6, xg7;
    {
      const u16* xpa = xproj + (size_t)(t * 32 + b0) * 4096 + hid0 + jj;
      const u16* xpb = xproj + (size_t)(t * 32 + b1) * 4096 + hid0 + jj;
      xg0 = bf2f(xpa[0]); xg1 = bf2f(xpa[1024]);
      xg2 = bf2f(xpa[2048]); xg3 = bf2f(xpa[3072]);
      xg4 = bf2f(xpb[0]); xg5 = bf2f(xpb[1024]);
      xg6 = bf2f(xpb[2048]); xg7 = bf2f(xpb[3072]);
      asm volatile("" : "+v"(xg0), "+v"(xg1), "+v"(xg2), "+v"(xg3),
                        "+v"(xg4), "+v"(xg5), "+v"(xg6), "+v"(xg7));
    }

    // tag-verified retry load of exactly the needed A-fragments
    u64 d[2][4][2];
    bool ok = false;
    while (!ok) {
#pragma unroll
      for (int mi = 0; mi < 2; ++mi)
#pragma unroll
        for (int kk = 0; kk < 4; ++kk) {
          d[mi][kk][0] = __hip_atomic_load(&cur[aidx[mi][kk]],
                                           __ATOMIC_RELAXED, __HIP_MEMORY_SCOPE_AGENT);
          d[mi][kk][1] = __hip_atomic_load(&cur[aidx[mi][kk] + 1],
                                           __ATOMIC_RELAXED, __HIP_MEMORY_SCOPE_AGENT);
        }
      u64 bad = 0;
#pragma unroll
      for (int mi = 0; mi < 2; ++mi)
#pragma unroll
        for (int kk = 0; kk < 4; ++kk)
          bad |= ((d[mi][kk][0] ^ E) | (d[mi][kk][1] ^ E)) & M;
      ok = (bad == 0);
      if (!ok) __builtin_amdgcn_s_sleep(1);
    }

    // MFMA + ds_add reduce, in two ni-halves to bound live acc registers
    {
      f32x4 acc[2][4];
#pragma unroll
      for (int a = 0; a < 2; ++a)
#pragma unroll
        for (int bb = 0; bb < 4; ++bb) acc[a][bb] = {0.f, 0.f, 0.f, 0.f};
#pragma unroll
      for (int kk = 0; kk < 4; ++kk)
#pragma unroll
        for (int mi = 0; mi < 2; ++mi) {
          union { u64 dd[2]; short8 s; } u;
          u.dd[0] = d[mi][kk][0]; u.dd[1] = d[mi][kk][1];
#pragma unroll
          for (int ni = 0; ni < 4; ++ni)
            acc[mi][ni] = __builtin_amdgcn_mfma_f32_16x16x32_bf16(
                u.s, bfr[ni][kk], acc[mi][ni], 0, 0, 0);
        }
#pragma unroll
      for (int mi = 0; mi < 2; ++mi)
#pragma unroll
        for (int ni = 0; ni < 4; ++ni)
#pragma unroll
          for (int r = 0; r < 4; ++r)
            unsafeAtomicAdd(&pg[mi * 16 + q * 4 + r][ni * 16 + bl],
                            acc[mi][ni][r]);
    }
    {
      f32x4 acc[2][4];
#pragma unroll
      for (int a = 0; a < 2; ++a)
#pragma unroll
        for (int bb = 0; bb < 4; ++bb) acc[a][bb] = {0.f, 0.f, 0.f, 0.f};
#pragma unroll
      for (int kk = 0; kk < 4; ++kk)
#pragma unroll
        for (int mi = 0; mi < 2; ++mi) {
          union { u64 dd[2]; short8 s; } u;
          u.dd[0] = d[mi][kk][0]; u.dd[1] = d[mi][kk][1];
#pragma unroll
          for (int ni = 0; ni < 4; ++ni)
            acc[mi][ni] = __builtin_amdgcn_mfma_f32_16x16x32_bf16(
                u.s, bfr[4 + ni][kk], acc[mi][ni], 0, 0, 0);
        }
#pragma unroll
      for (int mi = 0; mi < 2; ++mi)
#pragma unroll
        for (int ni = 0; ni < 4; ++ni)
#pragma unroll
          for (int r = 0; r < 4; ++r)
            unsafeAtomicAdd(&pg[mi * 16 + q * 4 + r][(4 + ni) * 16 + bl],
                            acc[mi][ni][r]);
    }
    __syncthreads();

    // epilogue: every thread owns 2 (batch, hid) pairs
    float gi0 = pg[b0][jj]      + xg0;
    float gf0 = pg[b0][32 + jj] + xg1;
    float gg0 = pg[b0][64 + jj] + xg2;
    float go0 = pg[b0][96 + jj] + xg3;
    float gi1 = pg[b1][jj]      + xg4;
    float gf1 = pg[b1][32 + jj] + xg5;
    float gg1 = pg[b1][64 + jj] + xg6;
    float go1 = pg[b1][96 + jj] + xg7;

    float i0 = 1.f / (1.f + __expf(-gi0));
    float f0 = 1.f / (1.f + __expf(-gf0));
    float g0 = 1.f - 2.f / (__expf(2.f * gg0) + 1.f);
    float o0 = 1.f / (1.f + __expf(-go0));
    cs0 = f0 * cs0 + i0 * g0;
    float h0v = o0 * (1.f - 2.f / (__expf(2.f * cs0) + 1.f));

    float i1 = 1.f / (1.f + __expf(-gi1));
    float f1 = 1.f / (1.f + __expf(-gf1));
    float g1 = 1.f - 2.f / (__expf(2.f * gg1) + 1.f);
    float o1 = 1.f / (1.f + __expf(-go1));
    cs1 = f1 * cs1 + i1 * g1;
    float h1v = o1 * (1.f - 2.f / (__expf(2.f * cs1) + 1.f));

    if (t < 511) {
      u16 ntag = (u16)((((t + 1) >> 1) + 1) & 1);
      u16 hv0 = (u16)((f2bf(h0v) & 0xFFFEu) | ntag);
      u16 hv1 = (u16)((f2bf(h1v) & 0xFFFEu) | ntag);
      // bound in-flight writes per slot to one epoch before publishing
      asm volatile("s_waitcnt vmcnt(0)" ::: "memory");
      __hip_atomic_store(&nxt[b0 * 1024 + hid0 + jj], hv0,
                         __ATOMIC_RELAXED, __HIP_MEMORY_SCOPE_AGENT);
      __hip_atomic_store(&nxt[b1 * 1024 + hid0 + jj], hv1,
                         __ATOMIC_RELAXED, __HIP_MEMORY_SCOPE_AGENT);
    }
    out[(size_t)b0 * 524288 + (size_t)t * 1024 + hid0 + jj] = h0v;
    out[(size_t)b1 * 524288 + (size_t)t * 1024 + hid0 + jj] = h1v;
    if (t == 511) {
      out[16777216 + b0 * 1024 + hid0 + jj] = h0v;           // h_T
      out[16777216 + b1 * 1024 + hid0 + jj] = h1v;
      out[16777216 + 32768 + b0 * 1024 + hid0 + jj] = cs0;   // c_T
      out[16777216 + 32768 + b1 * 1024 + hid0 + jj] = cs1;
    }

    // re-zero exactly the 8 entries this thread read (no race: unique reader)
#pragma unroll
    for (int g = 0; g < 4; ++g) {
      pg[b0][g * 32 + jj] = 0.f;
      pg[b1][g * 32 + jj] = 0.f;
    }
    __syncthreads();  // pg reused next iteration
  }
}

// ---------------- launch ------------------------------------------------------
extern "C" void kernel_launch(void* const* d_in, const int* in_sizes, int n_in,
                              void* d_out, int out_size, void* d_ws, size_t ws_size,
                              hipStream_t stream) {
  const float* x  = (const float*)d_in[0];
  const float* h0 = (const float*)d_in[1];
  const float* c0 = (const float*)d_in[2];
  const float* Wi = (const float*)d_in[3];
  const float* bi = (const float*)d_in[4];
  const float* Wh = (const float*)d_in[5];
  const float* bh = (const float*)d_in[6];
  float* out = (float*)d_out;

  // workspace layout (all 16B aligned)
  u16*   xbf   = (u16*)d_ws;                       // 33,554,432 B
  u16*   wibf  = xbf + NX;                         //  8,388,608 B
  float* bias  = (float*)(wibf + NWI);             //     16,384 B
  u16*   xproj = (u16*)(bias + 4096);              // 134,217,728 B
  u16*   hbuf  = xproj + (size_t)16384 * 4096;     //    131,072 B (2 x 64KB slots)

  prep_kernel<<<2048, 256, 0, stream>>>(x, Wi, bi, bh, xbf, wibf, bias);
  gemm_xproj<<<dim3(32, 128), 256, 0, stream>>>(xbf, wibf, bias, xproj);
  lstm_rec<<<32, 512, 0, stream>>>(Wh, xproj, h0, c0, out, hbuf);
}